// Round 10
// baseline (504.714 us; speedup 1.0000x reference)
//
#include <hip/hip_runtime.h>

// GCN: N=100000, E=1600000, widths 128 -> 16 -> 64 -> 128 -> 1
// Round 10: XCD channel-sharding for the 64-ch gather. R9 showed gather64 at
// the per-CU L2-miss throughput ceiling (13 B/cy/CU, 271 MB misses: 25.6 MB
// working set >> 4 MB per-XCD L2). Fix: g16gemm2 writes C group-blocked
// Cb[grp][node][8ch] (3.2 MB/slab); gather64 blocks pick grp = blockIdx&7,
// which round-robins onto XCDs, so each XCD's L2 holds exactly its slab.
// Pipeline: gemm1 -> gather16(r1) -> g16gemm2(r2, blocked) -> gather64x -> head.

#define NN 100000
#define NE 1600000
#define NB ((NN + 255) / 256)   // 391 blocks for scans

__device__ __forceinline__ float rdl_f(float v, int l) {
    return __int_as_float(__builtin_amdgcn_readlane(__float_as_int(v), l));
}

// ---------------- histogram + rank ----------------
__global__ void hist_rank_k(const int* __restrict__ dst, int* __restrict__ ideg,
                            int* __restrict__ rank, int e) {
    int i = blockIdx.x * blockDim.x + threadIdx.x;
    if (i < e) rank[i] = atomicAdd(&ideg[dst[i]], 1);
}

__global__ void dinv_k(const int* __restrict__ ideg, float* __restrict__ dinv, int n) {
    int i = blockIdx.x * blockDim.x + threadIdx.x;
    if (i < n) dinv[i] = rsqrtf((float)ideg[i] + 1.0f);  // +1 self loop
}

// ---------------- exclusive scan (3 kernels) ----------------
__global__ void scan_reduce_k(const int* __restrict__ ideg, int* __restrict__ bsum, int n) {
    __shared__ int s[256];
    int i = blockIdx.x * 256 + threadIdx.x;
    s[threadIdx.x] = (i < n) ? ideg[i] : 0;
    __syncthreads();
    for (int off = 128; off > 0; off >>= 1) {
        if (threadIdx.x < off) s[threadIdx.x] += s[threadIdx.x + off];
        __syncthreads();
    }
    if (threadIdx.x == 0) bsum[blockIdx.x] = s[0];
}

__global__ __launch_bounds__(512) void scan_partials_k(const int* __restrict__ bsum,
                                                       int* __restrict__ bofs, int nb) {
    __shared__ int s[512];
    int t = threadIdx.x;
    int v = (t < nb) ? bsum[t] : 0;
    s[t] = v;
    __syncthreads();
    for (int off = 1; off < 512; off <<= 1) {
        int a = (t >= off) ? s[t - off] : 0;
        __syncthreads();
        s[t] += a;
        __syncthreads();
    }
    if (t < nb) bofs[t] = s[t] - v;  // exclusive
}

__global__ void scan_final_k(const int* __restrict__ ideg, const int* __restrict__ bofs,
                             int* __restrict__ rowptr, int n, int e) {
    __shared__ int s[256];
    int i = blockIdx.x * 256 + threadIdx.x;
    int t = threadIdx.x;
    int v = (i < n) ? ideg[i] : 0;
    s[t] = v;
    __syncthreads();
    for (int off = 1; off < 256; off <<= 1) {
        int a = (t >= off) ? s[t - off] : 0;
        __syncthreads();
        s[t] += a;
        __syncthreads();
    }
    int excl = s[t] - v + bofs[blockIdx.x];
    if (i < n) rowptr[i] = excl;
    if (i == 0) rowptr[n] = e;
}

// ---------------- CSR fill: no atomics ----------------
__global__ void fill_k(const int* __restrict__ src, const int* __restrict__ dst,
                       const int* __restrict__ rank, const int* __restrict__ rowptr,
                       int* __restrict__ csr_src, int e) {
    int i = blockIdx.x * blockDim.x + threadIdx.x;
    if (i < e) csr_src[rowptr[dst[i]] + rank[i]] = src[i];
}

// ---------------- dense layer: out = scale? dinv[g]*act(in@W + b) ----------------
template<int K, int M, bool BIAS_RELU, bool SCALE>
__global__ __launch_bounds__(256) void gemm_k(const float* __restrict__ in,
                                              const float* __restrict__ bias,
                                              const float* __restrict__ W,
                                              const float* __restrict__ dinv,
                                              float* __restrict__ out, int n) {
    constexpr int ROWS = 256 / M;
    constexpr int KV = K / 4;
    __shared__ float sW[K * M];
    __shared__ float sIn[ROWS][K + 4];      // +4 pad: kill 4-way bank conflict
    const int tid = threadIdx.x;
    for (int i = tid; i < K * M; i += 256) sW[i] = W[i];
    const int row0 = blockIdx.x * ROWS;
    const float4* in4 = (const float4*)in;
    for (int i = tid; i < ROWS * KV; i += 256) {
        int r = i / KV, kv = i - r * KV;
        int g = row0 + r;
        float4 v = make_float4(0.f, 0.f, 0.f, 0.f);
        if (g < n) v = in4[(long)g * KV + kv];
        ((float4*)&sIn[r][0])[kv] = v;
    }
    __syncthreads();
    const int r = tid / M, m = tid - r * M;
    const int g = row0 + r;
    if (g < n) {
        float acc = 0.0f;
#pragma unroll
        for (int k = 0; k < K; ++k) acc += sIn[r][k] * sW[k * M + m];
        if (BIAS_RELU) acc = fmaxf(acc + bias[m], 0.0f);
        if (SCALE) acc *= dinv[g];
        out[(long)g * M + m] = acc;
    }
}

// ---------------- pull-gather, 16 ch (weight-free) ----------------
template<bool BIAS_RELU, bool OUT_SCALE>
__global__ __launch_bounds__(256) void gather16_k(const int* __restrict__ rowptr,
                                                  const int* __restrict__ csr_src,
                                                  const float* __restrict__ dinv,
                                                  const float* __restrict__ hs,
                                                  const float* __restrict__ bias,
                                                  float* __restrict__ outp, int n) {
    const int g = (blockIdx.x * 256 + threadIdx.x) >> 6;
    if (g >= n) return;
    const int lane = threadIdx.x & 63;
    const int q = lane & 3;                 // float4 index within 16-ch row
    const int sub = lane >> 2;              // edge subgroup 0..15
    const float dg = dinv[g];
    const int beg = rowptr[g], end = rowptr[g + 1];
    const float4* h4 = (const float4*)hs;
    float4 acc = make_float4(0.f, 0.f, 0.f, 0.f);
    if (sub == 0) acc = h4[(long)g * 4 + q];  // self term
    for (int j0 = beg; j0 < end; j0 += 16) {
        int idx = j0 + sub;
        if (idx < end) {
            const int s = csr_src[idx];
            const float4 v = h4[(long)s * 4 + q];
            acc.x += v.x; acc.y += v.y; acc.z += v.z; acc.w += v.w;
        }
    }
#pragma unroll
    for (int m = 4; m <= 32; m <<= 1) {
        acc.x += __shfl_xor(acc.x, m, 64);
        acc.y += __shfl_xor(acc.y, m, 64);
        acc.z += __shfl_xor(acc.z, m, 64);
        acc.w += __shfl_xor(acc.w, m, 64);
    }
    if (sub == 0) {
        float4 v = make_float4(acc.x * dg, acc.y * dg, acc.z * dg, acc.w * dg);
        if (BIAS_RELU) {
            const float4 b = ((const float4*)bias)[q];
            v.x = fmaxf(v.x + b.x, 0.0f);
            v.y = fmaxf(v.y + b.y, 0.0f);
            v.z = fmaxf(v.z + b.z, 0.0f);
            v.w = fmaxf(v.w + b.w, 0.0f);
        }
        if (OUT_SCALE) { v.x *= dg; v.y *= dg; v.z *= dg; v.w *= dg; }
        ((float4*)outp)[(long)g * 4 + q] = v;
    }
}

// ---------------- fused gather16 + gemm2, GROUP-BLOCKED output ----------------
// Cb[grp][node][8ch], grp = lane>>3: slab stride n*8 floats (3.2 MB).
__global__ __launch_bounds__(256) void g16gemm2_k(const int* __restrict__ rowptr,
                                                  const int* __restrict__ csr_src,
                                                  const float* __restrict__ dinv,
                                                  const float* __restrict__ hs,
                                                  const float* __restrict__ W2,
                                                  const float* __restrict__ b2,
                                                  float* __restrict__ outp, int n) {
    const int lane = threadIdx.x & 63;
    const int wid = blockIdx.x * 4 + (threadIdx.x >> 6);
    const int nWaves = gridDim.x * 4;
    float w2[16];
#pragma unroll
    for (int k = 0; k < 16; ++k) w2[k] = W2[k * 64 + lane];
    const float bm = b2[lane];
    const int q = lane & 3;
    const int sub = lane >> 2;
    const long slab = (long)n * 8;
    float* outg = outp + (long)(lane >> 3) * slab + (lane & 7);
    const float4* h4 = (const float4*)hs;
    for (int g = wid; g < n; g += nWaves) {
        const float dg = dinv[g];
        const int beg = rowptr[g], end = rowptr[g + 1];
        float4 acc = make_float4(0.f, 0.f, 0.f, 0.f);
        if (sub == 0) acc = h4[(long)g * 4 + q];  // self term
        for (int j0 = beg; j0 < end; j0 += 16) {
            int idx = j0 + sub;
            if (idx < end) {
                const int s = csr_src[idx];
                const float4 v = h4[(long)s * 4 + q];
                acc.x += v.x; acc.y += v.y; acc.z += v.z; acc.w += v.w;
            }
        }
#pragma unroll
        for (int m = 4; m <= 32; m <<= 1) {
            acc.x += __shfl_xor(acc.x, m, 64);
            acc.y += __shfl_xor(acc.y, m, 64);
            acc.z += __shfl_xor(acc.z, m, 64);
            acc.w += __shfl_xor(acc.w, m, 64);
        }
        float t = 0.0f;
#pragma unroll
        for (int ql = 0; ql < 4; ++ql) {
            t = fmaf(rdl_f(acc.x, ql), w2[4 * ql + 0], t);
            t = fmaf(rdl_f(acc.y, ql), w2[4 * ql + 1], t);
            t = fmaf(rdl_f(acc.z, ql), w2[4 * ql + 2], t);
            t = fmaf(rdl_f(acc.w, ql), w2[4 * ql + 3], t);
        }
        float r = fmaxf(fmaf(dg, t, bm), 0.0f);   // dg*(sum)@W2 + b2, relu
        outg[(long)g * 8] = r * dg;                // pre-scaled, blocked layout
    }
}

// ---------------- XCD-sharded 64-ch gather ----------------
// Block handles channel group grp = blockIdx&7 (round-robins onto XCD grp);
// wave = 8 edge-subs x 8 ch-lanes, 32 B contiguous read per edge from the
// group's 3.2 MB slab (L2-resident per XCD). Output standard row-major.
__global__ __launch_bounds__(256) void gather64x_k(const int* __restrict__ rowptr,
                                                   const int* __restrict__ csr_src,
                                                   const float* __restrict__ dinv,
                                                   const float* __restrict__ Cb,
                                                   float* __restrict__ outp, int n) {
    const int lane = threadIdx.x & 63;
    const int sub = lane >> 3;              // edge subgroup 0..7
    const int c = lane & 7;                 // channel within group
    const int grp = blockIdx.x & 7;
    const int wid = (blockIdx.x >> 3) * 4 + (threadIdx.x >> 6);
    const int nW = (gridDim.x >> 3) * 4;
    const float* Cg = Cb + (long)grp * ((long)n * 8) + c;
    for (int g = wid; g < n; g += nW) {
        const float dg = dinv[g];
        const int beg = rowptr[g], end = rowptr[g + 1];
        float acc = (sub == 0) ? Cg[(long)g * 8] : 0.0f;  // self term
        int j0 = beg;
        for (; j0 + 16 <= end; j0 += 16) {
            const int sA = csr_src[j0 + sub];
            const int sB = csr_src[j0 + 8 + sub];
            const float vA = Cg[(long)sA * 8];
            const float vB = Cg[(long)sB * 8];
            acc += vA + vB;
        }
        for (; j0 < end; j0 += 8) {
            int idx = j0 + sub;
            if (idx < end) acc += Cg[(long)csr_src[idx] * 8];
        }
        acc += __shfl_xor(acc, 8, 64);
        acc += __shfl_xor(acc, 16, 64);
        acc += __shfl_xor(acc, 32, 64);
        if (sub == 0) outp[(long)g * 64 + grp * 8 + c] = acc * dg;
    }
}

// ---------------- zero-LDS head: W3 in VGPRs, readlane broadcast ----------------
__global__ __launch_bounds__(256) void head_k(const float* __restrict__ aggS2,
                                              const float* __restrict__ W3,
                                              const float* __restrict__ b3,
                                              const float* __restrict__ Wfc,
                                              const float* __restrict__ bfc,
                                              float* __restrict__ out, int n) {
    const int lane = threadIdx.x & 63;
    const int wid = blockIdx.x * 4 + (threadIdx.x >> 6);
    const int nWaves = gridDim.x * 4;
    float w0[64], w1[64];
#pragma unroll
    for (int k = 0; k < 64; ++k) {
        w0[k] = W3[k * 128 + lane];
        w1[k] = W3[k * 128 + lane + 64];
    }
    const float bm0 = b3[lane], bm1 = b3[lane + 64];
    const float wf0 = Wfc[lane], wf1 = Wfc[lane + 64];
    const float bb = bfc[0];
    for (int g0 = wid * 4; g0 < n; g0 += nWaves * 4) {
        const float* base = aggS2 + (long)g0 * 64 + lane;
        const float rv0 = base[0];
        const float rv1 = base[64];
        const float rv2 = base[128];
        const float rv3 = base[192];
        float a00 = 0.f, a01 = 0.f, a10 = 0.f, a11 = 0.f;
        float a20 = 0.f, a21 = 0.f, a30 = 0.f, a31 = 0.f;
#pragma unroll
        for (int k = 0; k < 64; ++k) {
            const float x0 = rdl_f(rv0, k);
            const float x1 = rdl_f(rv1, k);
            const float x2 = rdl_f(rv2, k);
            const float x3 = rdl_f(rv3, k);
            a00 = fmaf(x0, w0[k], a00); a01 = fmaf(x0, w1[k], a01);
            a10 = fmaf(x1, w0[k], a10); a11 = fmaf(x1, w1[k], a11);
            a20 = fmaf(x2, w0[k], a20); a21 = fmaf(x2, w1[k], a21);
            a30 = fmaf(x3, w0[k], a30); a31 = fmaf(x3, w1[k], a31);
        }
        float v0 = fmaxf(a00 + bm0, 0.f) * wf0 + fmaxf(a01 + bm1, 0.f) * wf1;
        float v1 = fmaxf(a10 + bm0, 0.f) * wf0 + fmaxf(a11 + bm1, 0.f) * wf1;
        float v2 = fmaxf(a20 + bm0, 0.f) * wf0 + fmaxf(a21 + bm1, 0.f) * wf1;
        float v3 = fmaxf(a30 + bm0, 0.f) * wf0 + fmaxf(a31 + bm1, 0.f) * wf1;
#pragma unroll
        for (int off = 32; off > 0; off >>= 1) {
            v0 += __shfl_down(v0, off, 64);
            v1 += __shfl_down(v1, off, 64);
            v2 += __shfl_down(v2, off, 64);
            v3 += __shfl_down(v3, off, 64);
        }
        if (lane == 0)
            ((float4*)out)[g0 >> 2] = make_float4(v0 + bb, v1 + bb, v2 + bb, v3 + bb);
    }
}

extern "C" void kernel_launch(void* const* d_in, const int* in_sizes, int n_in,
                              void* d_out, int out_size, void* d_ws, size_t ws_size,
                              hipStream_t stream) {
    const float* x    = (const float*)d_in[0];
    const int*   ei   = (const int*)d_in[1];       // [2,E]: src = ei, dst = ei+E
    const float* W1   = (const float*)d_in[2];
    const float* b1   = (const float*)d_in[3];
    const float* W2   = (const float*)d_in[4];
    const float* b2   = (const float*)d_in[5];
    const float* W3   = (const float*)d_in[6];
    const float* b3   = (const float*)d_in[7];
    const float* Wfc  = (const float*)d_in[8];
    const float* bfc  = (const float*)d_in[9];
    float* out = (float*)d_out;

    const int* src = ei;
    const int* dst = ei + NE;

    // workspace layout (4-byte elems; arena offsets 16B-aligned):
    // dinv[N] | ideg[N] | rowptr[N+8] | bsum[512] | bofs[512] | rank[E]
    // | csr_src[E+64] | A[64N] | B[64N] | C[64N]
    float* dinv    = (float*)d_ws;
    int*   ideg    = (int*)(dinv + NN);
    int*   rowptr  = ideg + NN;
    int*   bsum    = rowptr + NN + 8;
    int*   bofs    = bsum + 512;
    int*   rank    = bofs + 512;
    int*   csr_src = rank + NE;
    float* A       = (float*)(csr_src + NE + 64);
    float* B       = A + (long)NN * 64;
    float* C       = B + (long)NN * 64;

    const int T = 256;

    // ---- CSR + norm build ----
    hipMemsetAsync(ideg, 0, NN * sizeof(int), stream);
    hist_rank_k<<<(NE + T - 1) / T, T, 0, stream>>>(dst, ideg, rank, NE);
    dinv_k<<<(NN + T - 1) / T, T, 0, stream>>>(ideg, dinv, NN);
    scan_reduce_k<<<NB, T, 0, stream>>>(ideg, bsum, NN);
    scan_partials_k<<<1, 512, 0, stream>>>(bsum, bofs, NB);
    scan_final_k<<<NB, T, 0, stream>>>(ideg, bofs, rowptr, NN, NE);
    fill_k<<<(NE + T - 1) / T, T, 0, stream>>>(src, dst, rank, rowptr, csr_src, NE);

    // ---- L1 GEMM: A = dinv * (x@W1)  (pre-scaled, 16ch) ----
    gemm_k<128, 16, false, true><<<(NN + 15) / 16, T, 0, stream>>>(x, nullptr, W1, dinv, A, NN);
    // ---- B = dinv * relu(dg*(sum A) + b1)  (pre-scaled r1, 16ch) ----
    gather16_k<true, true><<<(NN + 3) / 4, T, 0, stream>>>(rowptr, csr_src, dinv, A, b1, B, NN);
    // ---- C(blocked) = dinv * relu(dg*(sum B)@W2 + b2)  (pre-scaled r2, 64ch) ----
    g16gemm2_k<<<3072, T, 0, stream>>>(rowptr, csr_src, dinv, B, W2, b2, C, NN);
    // ---- A(64ch, row-major) = dg * sum C  (XCD-sharded gather) ----
    gather64x_k<<<8192, T, 0, stream>>>(rowptr, csr_src, dinv, C, A, NN);
    // ---- head: out = relu(A@W3 + b3).Wfc + bfc ----
    head_k<<<1024, T, 0, stream>>>(A, W3, b3, Wfc, bfc, out, NN);
}

// Round 11
// 410.859 us; speedup vs baseline: 1.2284x; 1.2284x over previous
//
#include <hip/hip_runtime.h>

// GCN: N=100000, E=1600000, widths 128 -> 16 -> 64 -> 128 -> 1
// Round 11: revert R10's channel-sharded gather64 (traffic won 271->74 MB but
// 8x edge traversal + scalar loads made it issue-bound: 81->172 us). Back to
// R9's float4 gather64. New: fill_k + gemm1 fused by block-range (independent
// work, overlap gemm1's VALU under fill's memory stalls); dinv fused into
// scan_reduce; head grid 2048.
// Pipeline: hist_rank -> scan(+dinv) -> fill+gemm1 -> gather16(r1)
//           -> g16gemm2(r2) -> gather64 -> head.

#define NN 100000
#define NE 1600000
#define NB ((NN + 255) / 256)   // 391 blocks for scans

__device__ __forceinline__ float rdl_f(float v, int l) {
    return __int_as_float(__builtin_amdgcn_readlane(__float_as_int(v), l));
}

// ---------------- histogram + rank ----------------
__global__ void hist_rank_k(const int* __restrict__ dst, int* __restrict__ ideg,
                            int* __restrict__ rank, int e) {
    int i = blockIdx.x * blockDim.x + threadIdx.x;
    if (i < e) rank[i] = atomicAdd(&ideg[dst[i]], 1);
}

// ---------------- scan pass 1 (+ fused dinv) ----------------
__global__ void scan_reduce_k(const int* __restrict__ ideg, int* __restrict__ bsum,
                              float* __restrict__ dinv, int n) {
    __shared__ int s[256];
    int i = blockIdx.x * 256 + threadIdx.x;
    int v = (i < n) ? ideg[i] : 0;
    if (i < n) dinv[i] = rsqrtf((float)v + 1.0f);  // +1 self loop
    s[threadIdx.x] = v;
    __syncthreads();
    for (int off = 128; off > 0; off >>= 1) {
        if (threadIdx.x < off) s[threadIdx.x] += s[threadIdx.x + off];
        __syncthreads();
    }
    if (threadIdx.x == 0) bsum[blockIdx.x] = s[0];
}

__global__ __launch_bounds__(512) void scan_partials_k(const int* __restrict__ bsum,
                                                       int* __restrict__ bofs, int nb) {
    __shared__ int s[512];
    int t = threadIdx.x;
    int v = (t < nb) ? bsum[t] : 0;
    s[t] = v;
    __syncthreads();
    for (int off = 1; off < 512; off <<= 1) {
        int a = (t >= off) ? s[t - off] : 0;
        __syncthreads();
        s[t] += a;
        __syncthreads();
    }
    if (t < nb) bofs[t] = s[t] - v;  // exclusive
}

__global__ void scan_final_k(const int* __restrict__ ideg, const int* __restrict__ bofs,
                             int* __restrict__ rowptr, int n, int e) {
    __shared__ int s[256];
    int i = blockIdx.x * 256 + threadIdx.x;
    int t = threadIdx.x;
    int v = (i < n) ? ideg[i] : 0;
    s[t] = v;
    __syncthreads();
    for (int off = 1; off < 256; off <<= 1) {
        int a = (t >= off) ? s[t - off] : 0;
        __syncthreads();
        s[t] += a;
        __syncthreads();
    }
    int excl = s[t] - v + bofs[blockIdx.x];
    if (i < n) rowptr[i] = excl;
    if (i == 0) rowptr[n] = e;
}

// ---------------- fused: CSR fill (blocks < fillBlocks) + gemm1 (rest) ----------------
// Independent work items sharing one dispatch so gemm1's VALU blocks overlap
// fill's scattered-store stalls. gemm1: A = dinv * (x @ W1), K=128, M=16.
__global__ __launch_bounds__(256) void fill_gemm1_k(const int* __restrict__ src,
                                                    const int* __restrict__ dst,
                                                    const int* __restrict__ rank,
                                                    const int* __restrict__ rowptr,
                                                    int* __restrict__ csr_src,
                                                    const float* __restrict__ x,
                                                    const float* __restrict__ W1,
                                                    const float* __restrict__ dinv,
                                                    float* __restrict__ A,
                                                    int e, int n, int fillBlocks) {
    __shared__ float sW[128 * 16];
    __shared__ float sIn[16][132];           // +4 pad
    if ((int)blockIdx.x < fillBlocks) {
        int i = blockIdx.x * 256 + threadIdx.x;
        if (i < e) csr_src[rowptr[dst[i]] + rank[i]] = src[i];
        return;
    }
    const int bid = blockIdx.x - fillBlocks;
    const int tid = threadIdx.x;
    for (int i = tid; i < 128 * 16; i += 256) sW[i] = W1[i];
    const int row0 = bid * 16;
    const float4* in4 = (const float4*)x;
    for (int i = tid; i < 16 * 32; i += 256) {
        int r = i >> 5, kv = i & 31;
        int g = row0 + r;
        float4 v = make_float4(0.f, 0.f, 0.f, 0.f);
        if (g < n) v = in4[(long)g * 32 + kv];
        ((float4*)&sIn[r][0])[kv] = v;
    }
    __syncthreads();
    const int r = tid >> 4, m = tid & 15;
    const int g = row0 + r;
    if (g < n) {
        float acc = 0.0f;
#pragma unroll
        for (int k = 0; k < 128; ++k) acc += sIn[r][k] * sW[k * 16 + m];
        A[(long)g * 16 + m] = acc * dinv[g];
    }
}

// ---------------- pull-gather, 16 ch (weight-free) ----------------
template<bool BIAS_RELU, bool OUT_SCALE>
__global__ __launch_bounds__(256) void gather16_k(const int* __restrict__ rowptr,
                                                  const int* __restrict__ csr_src,
                                                  const float* __restrict__ dinv,
                                                  const float* __restrict__ hs,
                                                  const float* __restrict__ bias,
                                                  float* __restrict__ outp, int n) {
    const int g = (blockIdx.x * 256 + threadIdx.x) >> 6;
    if (g >= n) return;
    const int lane = threadIdx.x & 63;
    const int q = lane & 3;                 // float4 index within 16-ch row
    const int sub = lane >> 2;              // edge subgroup 0..15
    const float dg = dinv[g];
    const int beg = rowptr[g], end = rowptr[g + 1];
    const float4* h4 = (const float4*)hs;
    float4 acc = make_float4(0.f, 0.f, 0.f, 0.f);
    if (sub == 0) acc = h4[(long)g * 4 + q];  // self term
    for (int j0 = beg; j0 < end; j0 += 16) {
        int idx = j0 + sub;
        if (idx < end) {
            const int s = csr_src[idx];
            const float4 v = h4[(long)s * 4 + q];
            acc.x += v.x; acc.y += v.y; acc.z += v.z; acc.w += v.w;
        }
    }
#pragma unroll
    for (int m = 4; m <= 32; m <<= 1) {
        acc.x += __shfl_xor(acc.x, m, 64);
        acc.y += __shfl_xor(acc.y, m, 64);
        acc.z += __shfl_xor(acc.z, m, 64);
        acc.w += __shfl_xor(acc.w, m, 64);
    }
    if (sub == 0) {
        float4 v = make_float4(acc.x * dg, acc.y * dg, acc.z * dg, acc.w * dg);
        if (BIAS_RELU) {
            const float4 b = ((const float4*)bias)[q];
            v.x = fmaxf(v.x + b.x, 0.0f);
            v.y = fmaxf(v.y + b.y, 0.0f);
            v.z = fmaxf(v.z + b.z, 0.0f);
            v.w = fmaxf(v.w + b.w, 0.0f);
        }
        if (OUT_SCALE) { v.x *= dg; v.y *= dg; v.z *= dg; v.w *= dg; }
        ((float4*)outp)[(long)g * 4 + q] = v;
    }
}

// ---------------- fused gather16 + gemm2: C = dinv*relu(dg*(sum Bs)@W2 + b2) ----------------
__global__ __launch_bounds__(256) void g16gemm2_k(const int* __restrict__ rowptr,
                                                  const int* __restrict__ csr_src,
                                                  const float* __restrict__ dinv,
                                                  const float* __restrict__ hs,
                                                  const float* __restrict__ W2,
                                                  const float* __restrict__ b2,
                                                  float* __restrict__ outp, int n) {
    const int lane = threadIdx.x & 63;
    const int wid = blockIdx.x * 4 + (threadIdx.x >> 6);
    const int nWaves = gridDim.x * 4;
    float w2[16];
#pragma unroll
    for (int k = 0; k < 16; ++k) w2[k] = W2[k * 64 + lane];
    const float bm = b2[lane];
    const int q = lane & 3;
    const int sub = lane >> 2;
    const float4* h4 = (const float4*)hs;
    for (int g = wid; g < n; g += nWaves) {
        const float dg = dinv[g];
        const int beg = rowptr[g], end = rowptr[g + 1];
        float4 acc = make_float4(0.f, 0.f, 0.f, 0.f);
        if (sub == 0) acc = h4[(long)g * 4 + q];  // self term
        for (int j0 = beg; j0 < end; j0 += 16) {
            int idx = j0 + sub;
            if (idx < end) {
                const int s = csr_src[idx];
                const float4 v = h4[(long)s * 4 + q];
                acc.x += v.x; acc.y += v.y; acc.z += v.z; acc.w += v.w;
            }
        }
#pragma unroll
        for (int m = 4; m <= 32; m <<= 1) {
            acc.x += __shfl_xor(acc.x, m, 64);
            acc.y += __shfl_xor(acc.y, m, 64);
            acc.z += __shfl_xor(acc.z, m, 64);
            acc.w += __shfl_xor(acc.w, m, 64);
        }
        float t = 0.0f;
#pragma unroll
        for (int ql = 0; ql < 4; ++ql) {
            t = fmaf(rdl_f(acc.x, ql), w2[4 * ql + 0], t);
            t = fmaf(rdl_f(acc.y, ql), w2[4 * ql + 1], t);
            t = fmaf(rdl_f(acc.z, ql), w2[4 * ql + 2], t);
            t = fmaf(rdl_f(acc.w, ql), w2[4 * ql + 3], t);
        }
        float r = fmaxf(fmaf(dg, t, bm), 0.0f);   // dg*(sum)@W2 + b2, relu
        outp[(long)g * 64 + lane] = r * dg;        // pre-scaled for next gather
    }
}

// ---------------- pull-gather, 64 ch (R9 float4 version) ----------------
__global__ __launch_bounds__(256) void gather64_k(const int* __restrict__ rowptr,
                                                  const int* __restrict__ csr_src,
                                                  const float* __restrict__ dinv,
                                                  const float* __restrict__ hs,
                                                  float* __restrict__ outp, int n) {
    const int g = (blockIdx.x * 256 + threadIdx.x) >> 6;
    if (g >= n) return;
    const int lane = threadIdx.x & 63;
    const int q = lane & 15;                // float4 index within 64-ch row
    const int sub = lane >> 4;              // edge subgroup 0..3
    const float dg = dinv[g];
    const int beg = rowptr[g], end = rowptr[g + 1];
    const float4* h4 = (const float4*)hs;
    float4 acc = make_float4(0.f, 0.f, 0.f, 0.f);
    if (sub == 0) acc = h4[(long)g * 16 + q];  // self term
    int j0 = beg;
    for (; j0 + 8 <= end; j0 += 8) {
        const int s0 = csr_src[j0 + sub];
        const int s1 = csr_src[j0 + 4 + sub];
        const float4 v0 = h4[(long)s0 * 16 + q];
        const float4 v1 = h4[(long)s1 * 16 + q];
        acc.x += v0.x + v1.x; acc.y += v0.y + v1.y;
        acc.z += v0.z + v1.z; acc.w += v0.w + v1.w;
    }
    for (; j0 < end; j0 += 4) {
        int idx = j0 + sub;
        if (idx < end) {
            const int s = csr_src[idx];
            const float4 v = h4[(long)s * 16 + q];
            acc.x += v.x; acc.y += v.y; acc.z += v.z; acc.w += v.w;
        }
    }
#pragma unroll
    for (int m = 16; m <= 32; m <<= 1) {
        acc.x += __shfl_xor(acc.x, m, 64);
        acc.y += __shfl_xor(acc.y, m, 64);
        acc.z += __shfl_xor(acc.z, m, 64);
        acc.w += __shfl_xor(acc.w, m, 64);
    }
    if (sub == 0) {
        ((float4*)outp)[(long)g * 16 + q] =
            make_float4(acc.x * dg, acc.y * dg, acc.z * dg, acc.w * dg);
    }
}

// ---------------- zero-LDS head: W3 in VGPRs, readlane broadcast ----------------
__global__ __launch_bounds__(256) void head_k(const float* __restrict__ aggS2,
                                              const float* __restrict__ W3,
                                              const float* __restrict__ b3,
                                              const float* __restrict__ Wfc,
                                              const float* __restrict__ bfc,
                                              float* __restrict__ out, int n) {
    const int lane = threadIdx.x & 63;
    const int wid = blockIdx.x * 4 + (threadIdx.x >> 6);
    const int nWaves = gridDim.x * 4;
    float w0[64], w1[64];
#pragma unroll
    for (int k = 0; k < 64; ++k) {
        w0[k] = W3[k * 128 + lane];
        w1[k] = W3[k * 128 + lane + 64];
    }
    const float bm0 = b3[lane], bm1 = b3[lane + 64];
    const float wf0 = Wfc[lane], wf1 = Wfc[lane + 64];
    const float bb = bfc[0];
    for (int g0 = wid * 4; g0 < n; g0 += nWaves * 4) {
        const float* base = aggS2 + (long)g0 * 64 + lane;
        const float rv0 = base[0];
        const float rv1 = base[64];
        const float rv2 = base[128];
        const float rv3 = base[192];
        float a00 = 0.f, a01 = 0.f, a10 = 0.f, a11 = 0.f;
        float a20 = 0.f, a21 = 0.f, a30 = 0.f, a31 = 0.f;
#pragma unroll
        for (int k = 0; k < 64; ++k) {
            const float x0 = rdl_f(rv0, k);
            const float x1 = rdl_f(rv1, k);
            const float x2 = rdl_f(rv2, k);
            const float x3 = rdl_f(rv3, k);
            a00 = fmaf(x0, w0[k], a00); a01 = fmaf(x0, w1[k], a01);
            a10 = fmaf(x1, w0[k], a10); a11 = fmaf(x1, w1[k], a11);
            a20 = fmaf(x2, w0[k], a20); a21 = fmaf(x2, w1[k], a21);
            a30 = fmaf(x3, w0[k], a30); a31 = fmaf(x3, w1[k], a31);
        }
        float v0 = fmaxf(a00 + bm0, 0.f) * wf0 + fmaxf(a01 + bm1, 0.f) * wf1;
        float v1 = fmaxf(a10 + bm0, 0.f) * wf0 + fmaxf(a11 + bm1, 0.f) * wf1;
        float v2 = fmaxf(a20 + bm0, 0.f) * wf0 + fmaxf(a21 + bm1, 0.f) * wf1;
        float v3 = fmaxf(a30 + bm0, 0.f) * wf0 + fmaxf(a31 + bm1, 0.f) * wf1;
#pragma unroll
        for (int off = 32; off > 0; off >>= 1) {
            v0 += __shfl_down(v0, off, 64);
            v1 += __shfl_down(v1, off, 64);
            v2 += __shfl_down(v2, off, 64);
            v3 += __shfl_down(v3, off, 64);
        }
        if (lane == 0)
            ((float4*)out)[g0 >> 2] = make_float4(v0 + bb, v1 + bb, v2 + bb, v3 + bb);
    }
}

extern "C" void kernel_launch(void* const* d_in, const int* in_sizes, int n_in,
                              void* d_out, int out_size, void* d_ws, size_t ws_size,
                              hipStream_t stream) {
    const float* x    = (const float*)d_in[0];
    const int*   ei   = (const int*)d_in[1];       // [2,E]: src = ei, dst = ei+E
    const float* W1   = (const float*)d_in[2];
    const float* b1   = (const float*)d_in[3];
    const float* W2   = (const float*)d_in[4];
    const float* b2   = (const float*)d_in[5];
    const float* W3   = (const float*)d_in[6];
    const float* b3   = (const float*)d_in[7];
    const float* Wfc  = (const float*)d_in[8];
    const float* bfc  = (const float*)d_in[9];
    float* out = (float*)d_out;

    const int* src = ei;
    const int* dst = ei + NE;

    // workspace layout (4-byte elems; arena offsets 16B-aligned):
    // dinv[N] | ideg[N] | rowptr[N+8] | bsum[512] | bofs[512] | rank[E]
    // | csr_src[E+64] | A[64N] | B[64N] | C[64N]
    float* dinv    = (float*)d_ws;
    int*   ideg    = (int*)(dinv + NN);
    int*   rowptr  = ideg + NN;
    int*   bsum    = rowptr + NN + 8;
    int*   bofs    = bsum + 512;
    int*   rank    = bofs + 512;
    int*   csr_src = rank + NE;
    float* A       = (float*)(csr_src + NE + 64);
    float* B       = A + (long)NN * 64;
    float* C       = B + (long)NN * 64;

    const int T = 256;

    // ---- CSR + norm build ----
    hipMemsetAsync(ideg, 0, NN * sizeof(int), stream);
    hist_rank_k<<<(NE + T - 1) / T, T, 0, stream>>>(dst, ideg, rank, NE);
    scan_reduce_k<<<NB, T, 0, stream>>>(ideg, bsum, dinv, NN);
    scan_partials_k<<<1, 512, 0, stream>>>(bsum, bofs, NB);
    scan_final_k<<<NB, T, 0, stream>>>(ideg, bofs, rowptr, NN, NE);

    // ---- fused: CSR fill + gemm1 (A = dinv * x@W1, 16ch) ----
    const int fillBlocks = (NE + T - 1) / T;           // 6250
    const int gemmBlocks = (NN + 15) / 16;             // 6250
    fill_gemm1_k<<<fillBlocks + gemmBlocks, T, 0, stream>>>(
        src, dst, rank, rowptr, csr_src, x, W1, dinv, A, NE, NN, fillBlocks);

    // ---- B = dinv * relu(dg*(sum A) + b1)  (pre-scaled r1, 16ch) ----
    gather16_k<true, true><<<(NN + 3) / 4, T, 0, stream>>>(rowptr, csr_src, dinv, A, b1, B, NN);
    // ---- C = dinv * relu(dg*(sum B)@W2 + b2)  (pre-scaled r2, 64ch) ----
    g16gemm2_k<<<3072, T, 0, stream>>>(rowptr, csr_src, dinv, B, W2, b2, C, NN);
    // ---- A(64ch) = dg * sum C  (aggS2) ----
    gather64_k<<<(NN + 3) / 4, T, 0, stream>>>(rowptr, csr_src, dinv, C, A, NN);
    // ---- head: out = relu(A@W3 + b3).Wfc + bfc ----
    head_k<<<2048, T, 0, stream>>>(A, W3, b3, Wfc, bfc, out, NN);
}